// Round 1
// baseline (428.114 us; speedup 1.0000x reference)
//
#include <hip/hip_runtime.h>

#define N_COLS 8192
#define LOG2_COLS 13

// Fused kernel. Grid = 2048 blocks x 256 threads:
//   blockIdx & 7   -> which 1024-column tile (8 tiles cover 8192 cols)
//   blockIdx >> 3  -> which 32-row tile      (256 tiles cover 8192 rows)
//
// Phase 1: every block computes max(x) itself. x is 32 KiB -> L2-resident;
//          the redundant reduction is fully parallel across blocks and costs
//          a few microseconds total, cheaper than a separate kernel launch +
//          serialization.
// Phase 2: each thread owns 4 consecutive columns. It computes the spike
//          mask for those 4 columns in registers (bit-exact div->mul->floorf
//          chain, identical to the verified kernel), then loops over its 32
//          rows writing float4s: pure zero stores on the (common) no-spike
//          path, weight reads only for lanes whose group contains a spike.
//          Consecutive threads write consecutive 16 B -> each wave store is
//          a contiguous 1 KiB transaction.
__global__ __launch_bounds__(256) void fused_spike_mask(const float* __restrict__ x,
                                                        const float* __restrict__ w,
                                                        const int* __restrict__ t_ptr,
                                                        float* __restrict__ out) {
    __shared__ float smax[4];
    const int tid = threadIdx.x;  // 0..255

    // ---- Phase 1: block-wide max over x[0..8191] ----
    const float4* __restrict__ x4 = (const float4*)x;
    float m = -1e30f;
    float4 xv[8];
#pragma unroll
    for (int k = 0; k < 8; ++k) {
        xv[k] = x4[tid + (k << 8)];           // coalesced, covers all 2048 float4
        m = fmaxf(fmaxf(fmaxf(m, xv[k].x), fmaxf(xv[k].y, xv[k].z)), xv[k].w);
    }
#pragma unroll
    for (int off = 32; off > 0; off >>= 1)
        m = fmaxf(m, __shfl_down(m, off, 64));
    if ((tid & 63) == 0) smax[tid >> 6] = m;
    __syncthreads();
    const float maxv = fmaxf(fmaxf(smax[0], smax[1]), fmaxf(smax[2], smax[3]));

    // ---- Phase 2: per-thread 4-column spike mask, then 32-row tile write ----
    const int t = *t_ptr;
    const int g = ((blockIdx.x & 7) << 8) + tid;   // float4 group index 0..2047
    const int r0 = (blockIdx.x >> 3) << 5;         // first row of this block's tile

    // x for this thread's 4 columns (L1-hit; this block just read all of x)
    const float4 xc = x4[g];
    const int q0 = (int)floorf((xc.x / maxv) * 255.0f);
    const int q1 = (int)floorf((xc.y / maxv) * 255.0f);
    const int q2 = (int)floorf((xc.z / maxv) * 255.0f);
    const int q3 = (int)floorf((xc.w / maxv) * 255.0f);
    const float m0 = (q0 == t) ? 1.0f : 0.0f;
    const float m1 = (q1 == t) ? 1.0f : 0.0f;
    const float m2 = (q2 == t) ? 1.0f : 0.0f;
    const float m3 = (q3 == t) ? 1.0f : 0.0f;
    const bool any = (q0 == t) | (q1 == t) | (q2 == t) | (q3 == t);

    const float4* __restrict__ w4 = (const float4*)w;
    float4* __restrict__ o4 = (float4*)out;
    // index in float4 units: r * 2048 + g
    size_t idx4 = ((size_t)r0 << (LOG2_COLS - 2)) + (size_t)g;

    if (any) {
        // rare path: ~0.4% of lanes; exec-masked loads fetch only these lanes
#pragma unroll 8
        for (int r = 0; r < 32; ++r) {
            const float4 wv = w4[idx4];
            float4 ov;
            ov.x = wv.x * m0;
            ov.y = wv.y * m1;
            ov.z = wv.z * m2;
            ov.w = wv.w * m3;
            o4[idx4] = ov;
            idx4 += (N_COLS >> 2);
        }
    } else {
        const float4 z = {0.0f, 0.0f, 0.0f, 0.0f};
#pragma unroll 8
        for (int r = 0; r < 32; ++r) {
            o4[idx4] = z;
            idx4 += (N_COLS >> 2);
        }
    }
}

extern "C" void kernel_launch(void* const* d_in, const int* in_sizes, int n_in,
                              void* d_out, int out_size, void* d_ws, size_t ws_size,
                              hipStream_t stream) {
    const float* x = (const float*)d_in[0];   // [1, 8192] fp32
    const float* w = (const float*)d_in[1];   // [8192, 8192] fp32
    const int* t = (const int*)d_in[2];       // scalar int
    float* out = (float*)d_out;               // [8192, 8192] fp32

    // 2048 blocks = 8 col-tiles x 256 row-tiles; 8 blocks/CU, full occupancy.
    fused_spike_mask<<<2048, 256, 0, stream>>>(x, w, t, out);
}